// Round 4
// baseline (218.847 us; speedup 1.0000x reference)
//
#include <hip/hip_runtime.h>
#include <stdint.h>

#define F_IN 65536
#define NN 100
#define CO 60
#define G_SPLIT 128
#define KC (F_IN/G_SPLIT)   // 512
#define BK 32
#define NIT (KC/BK)         // 16
#define NBUF 3
#define ABYTES (112*BK*2)   // 7168
#define WBYTES (BK*CO*4)    // 7680
#define BUFB (ABYTES+WBYTES)// 14848; x3 = 44544 B LDS -> 3 blocks/CU

typedef short v8s __attribute__((ext_vector_type(8)));
typedef float v4f __attribute__((ext_vector_type(4)));

__device__ __forceinline__ unsigned int f2bf(float x){
  unsigned int u = __float_as_uint(x);
  u += 0x7fffu + ((u>>16)&1u);      // round-to-nearest-even
  return u>>16;
}
__device__ __forceinline__ v4f mfma16(v8s a, v8s b, v4f c){
  return __builtin_amdgcn_mfma_f32_16x16x32_bf16(a,b,c,0,0,0);
}
// async global->LDS, 16 B/lane; LDS dest = uniform base + lane*16 (HW rule).
__device__ __forceinline__ void cp16(const void* g, void* l){
  __builtin_amdgcn_global_load_lds((const __attribute__((address_space(1))) void*)g,
                                   (__attribute__((address_space(3))) void*)l, 16, 0, 0);
}

// ---------------------------------------------------------------------------
// K0: x (f32) -> xb (bf16), once.
// ---------------------------------------------------------------------------
__global__ __launch_bounds__(256)
void k_cvt(const float* __restrict__ x, unsigned short* __restrict__ xb){
  int i = blockIdx.x*256 + threadIdx.x;           // 6400*256*4 == 6,553,600 exactly
  float4 v = ((const float4*)x)[i];
  uint2 w;
  w.x = f2bf(v.x) | (f2bf(v.y)<<16);
  w.y = f2bf(v.z) | (f2bf(v.w)<<16);
  ((uint2*)xb)[i] = w;
}

// ---------------------------------------------------------------------------
// K1: split-K GEMM, 3-deep DMA ring + raw-barrier pipeline.
// grid=(G_SPLIT,6) = 768 blocks = exactly 3/CU (all co-resident, LDS 44.5 KB).
// Per iter, per wave: exactly 4 global_load_lds_dwordx4 (padded uniform), so
// `s_waitcnt vmcnt(4)` == "my previous batch landed"; then s_barrier makes it
// block-wide.  Prefetch distance 2 (3 LDS buffers): the drain at iter `it`
// waits on DMAs issued 2 compute-phases earlier -> latency hidden.
// A (bf16): 112x32 tile, rows 64 B, 16B chunks XOR-swizzled by (row&3) on the
// global side.  W (f32): 32x60 slab = 7680 B as 8x1KB (last overlapped, no OOB).
// ---------------------------------------------------------------------------
__global__ __launch_bounds__(256,3)
void k_gemm(const unsigned short* __restrict__ xb, const float* __restrict__ aw,
            const float* __restrict__ cw, float* __restrict__ dst, int partial){
  const int s = blockIdx.x, g = blockIdx.y;
  const int k0 = s*KC;
  const int tid = threadIdx.x, wave = tid>>6, lane = tid&63, quad = lane>>4, nl = lane&15;
  const int c0 = wave*16, ccl = min(c0+nl, CO-1);

  __shared__ __align__(16) char S[NBUF*BUFB];

  const float* W = (g<3) ? (aw + (size_t)g*F_IN*CO) : (cw + (size_t)(g-3)*F_IN*CO);

  // --- per-wave 4 DMA slots: ids 0..6 = A(t), 7..14 = W(t-7), 15 = dup A(0) ---
  const char* gsrc[4]; unsigned ldst[4]; unsigned gstep[4];
  #pragma unroll
  for(int i=0;i<4;++i){
    int id = wave*4 + i;
    if(id >= 15) id = 0;                       // pad slot duplicates A t=0 (idempotent)
    if(id < 7){                                // A instr t: 16 rows x 64 B
      int t = id;
      int row = t*16 + (lane>>2);
      int rcl = min(row, NN-1);                // rows 100..111 clone row 99
      int lch = (lane&3) ^ (row&3);            // XOR swizzle on global side
      gsrc[i]  = (const char*)(xb + (size_t)rcl*F_IN + k0) + lch*16;
      gstep[i] = BK*2;                         // 64 B per iter
      ldst[i]  = t*1024 + lane*16;
    } else {                                   // W instr t: contiguous 1 KB
      int t = id - 7;
      int off = t*1024; if(off > WBYTES-1024) off = WBYTES-1024;  // t=7 overlaps t=6 tail
      gsrc[i]  = (const char*)W + (size_t)k0*CO*4 + off + lane*16;
      gstep[i] = WBYTES;
      ldst[i]  = ABYTES + off + lane*16;
    }
  }

  v4f acc[7];
  #pragma unroll
  for(int i=0;i<7;++i){ v4f z={0.f,0.f,0.f,0.f}; acc[i]=z; }

  #define ISSUE(it) { char* b_ = S + ((it)%NBUF)*BUFB; \
    _Pragma("unroll") for(int i_=0;i_<4;++i_) cp16(gsrc[i_] + (size_t)(it)*gstep[i_], b_ + ldst[i_]); }

  #define COMPUTE(it) { const char* b_ = S + ((it)%NBUF)*BUFB; \
    const unsigned short* Ab_ = (const unsigned short*)b_; \
    const float* Wb_ = (const float*)(b_ + ABYTES); \
    v8s fB_; \
    _Pragma("unroll") for(int j_=0;j_<8;++j_) fB_[j_] = (short)f2bf(Wb_[(quad*8+j_)*CO + ccl]); \
    _Pragma("unroll") for(int mt_=0;mt_<7;++mt_){ \
      int r_ = mt_*16 + nl; \
      v8s a_ = *(const v8s*)(Ab_ + r_*BK + ((quad ^ (r_&3))*8)); \
      acc[mt_] = mfma16(a_, fB_, acc[mt_]); } }

  ISSUE(0); ISSUE(1);
  for(int it=0; it<NIT-1; ++it){
    __builtin_amdgcn_sched_barrier(0);
    asm volatile("s_waitcnt vmcnt(4)" ::: "memory");   // my batch(it) landed
    __builtin_amdgcn_s_barrier();                      // block-wide: buf(it) complete
    __builtin_amdgcn_sched_barrier(0);
    if(it+2 < NIT) ISSUE(it+2);                        // -> buf[(it+2)%3]: readers done at barrier
    COMPUTE(it);
  }
  __builtin_amdgcn_sched_barrier(0);
  asm volatile("s_waitcnt vmcnt(0)" ::: "memory");
  __builtin_amdgcn_s_barrier();
  __builtin_amdgcn_sched_barrier(0);
  COMPUTE(NIT-1);

  // --- epilogue.  C/D layout: col=lane&15, row=quad*4+i ---
  const int c = c0 + nl;
  if(c < CO){
    if(partial){
      float* pd = dst + ((size_t)g*G_SPLIT + s)*(NN*CO);
      #pragma unroll
      for(int mt=0;mt<7;++mt){
        #pragma unroll
        for(int i=0;i<4;++i){
          int m = mt*16 + quad*4 + i;
          if(m < NN) pd[m*CO + c] = acc[mt][i];
        }
      }
    } else {
      float* pd = dst + (size_t)g*(NN*CO);
      #pragma unroll
      for(int mt=0;mt<7;++mt){
        #pragma unroll
        for(int i=0;i<4;++i){
          int m = mt*16 + quad*4 + i;
          if(m < NN) atomicAdd(pd + m*CO + c, acc[mt][i]);
        }
      }
    }
  }
}

// ---------------------------------------------------------------------------
// K1b: split-K reduce.  grid=(141,4); block (b,q) sums 32 slices of P into Y
// via atomicAdd (Y zeroed by memset).  Reads coalesced (stride 6000 floats).
// ---------------------------------------------------------------------------
__global__ void k_reduce(const float* __restrict__ P, float* __restrict__ Y){
  int o = blockIdx.x*256 + threadIdx.x;
  if(o >= 6*NN*CO) return;
  int gg = o/(NN*CO), r = o - gg*(NN*CO);
  const float* p = P + (size_t)gg*G_SPLIT*(NN*CO) + (size_t)blockIdx.y*32*(NN*CO) + r;
  float a0=0.f,a1=0.f,a2=0.f,a3=0.f;
  #pragma unroll 2
  for(int s4=0;s4<32;s4+=4){
    a0 += p[(s4  )*(NN*CO)];
    a1 += p[(s4+1)*(NN*CO)];
    a2 += p[(s4+2)*(NN*CO)];
    a3 += p[(s4+3)*(NN*CO)];
  }
  atomicAdd(&Y[o], (a0+a1)+(a2+a3));
}

// ---------------------------------------------------------------------------
// K2: cheb combine.  out = Y0 - Y2 + L@(Y1 + 2*L@Y2) + b, then tanh.
// ---------------------------------------------------------------------------
__global__ void k_cheb(const float* __restrict__ Y, const int* __restrict__ ei,
                       const float* __restrict__ ab, const float* __restrict__ cb,
                       float* __restrict__ emb){
  const int net = blockIdx.x / CO;
  const int c   = blockIdx.x % CO;
  const int t   = threadIdx.x;       // 128
  __shared__ float L[NN][NN+1];
  __shared__ float dis[NN];
  __shared__ int   deg[NN];
  __shared__ float y0[NN], y1[NN], y2[NN], zu[NN];

  for(int i=t;i<NN*(NN+1);i+=128) ((float*)L)[i]=0.f;
  if(t<NN) deg[t]=0;
  __syncthreads();
  for(int e=t;e<2000;e+=128) atomicAdd(&deg[ei[e]],1);
  __syncthreads();
  if(t<NN) dis[t] = deg[t]>0 ? rsqrtf((float)deg[t]) : 0.f;
  __syncthreads();
  for(int e=t;e<2000;e+=128){
    int s = ei[e], d = ei[2000+e];
    atomicAdd(&L[d][s], -dis[s]*dis[d]);
  }
  if(t<NN){
    const float* yb = Y + (size_t)net*3*NN*CO + t*CO + c;
    y0[t]=yb[0]; y1[t]=yb[NN*CO]; y2[t]=yb[2*NN*CO];
  }
  __syncthreads();
  if(t<NN){
    float s=0.f;
    #pragma unroll 4
    for(int j=0;j<NN;++j) s += L[t][j]*y2[j];
    zu[t] = y1[t] + 2.f*s;
  }
  __syncthreads();
  if(t<NN){
    float s=0.f;
    #pragma unroll 4
    for(int j=0;j<NN;++j) s += L[t][j]*zu[j];
    float b = (net==0) ? ab[c] : cb[c];
    emb[net*NN*CO + t*CO + c] = tanhf(y0[t] - y2[t] + s + b);
  }
}

// ---------------------------------------------------------------------------
// K3: final FC.  out zeroed by memset.  Blocks 0..24: coalesced logits
// partials; block 25: value dot + biases + scalar extras.
// ---------------------------------------------------------------------------
#define FCB 25
__global__ void k_fc(const float* __restrict__ emb, const float* __restrict__ afw,
                     const float* __restrict__ afb, const float* __restrict__ cfw,
                     const float* __restrict__ cfb, const float* __restrict__ s0,
                     const float* __restrict__ s1, const float* __restrict__ s2,
                     float* __restrict__ out){
  const int b = blockIdx.x;
  const int t = threadIdx.x;         // 256
  if(b < FCB){
    const int jj = t & 127, half = t >> 7;
    if(jj < 100){
      const int i0 = b*240 + half*120;
      const float* w = afw + (size_t)i0*100 + jj;
      const float* e = emb + i0;
      float p = 0.f;
      #pragma unroll 4
      for(int i=0;i<120;++i) p += e[i]*w[(size_t)i*100];
      atomicAdd(&out[jj], p);
    }
  } else {
    float p = 0.f;
    const float* e = emb + 6000;
    for(int i=t;i<6000;i+=256) p += e[i]*cfw[i];
    #pragma unroll
    for(int o=32;o>0;o>>=1) p += __shfl_down(p,o,64);
    __shared__ float red[4];
    if((t&63)==0) red[t>>6]=p;
    __syncthreads();
    if(t==0){
      float tot = red[0]+red[1]+red[2]+red[3];
      out[100] = tot + s0[0]*cfw[6000] + s1[0]*cfw[6001] + s2[0]*cfw[6002] + cfb[0];
    }
    if(t<100){
      atomicAdd(&out[t], afb[t] + s0[0]*afw[600000+t] + s1[0]*afw[600100+t] + s2[0]*afw[600200+t]);
    }
  }
}

extern "C" void kernel_launch(void* const* d_in, const int* in_sizes, int n_in,
                              void* d_out, int out_size, void* d_ws, size_t ws_size,
                              hipStream_t stream){
  const float* x   = (const float*)d_in[0];
  const int*   ei  = (const int*)d_in[1];
  const float* s0  = (const float*)d_in[2];
  const float* s1  = (const float*)d_in[3];
  const float* s2  = (const float*)d_in[4];
  const float* aw  = (const float*)d_in[5];
  const float* ab  = (const float*)d_in[6];
  const float* cw  = (const float*)d_in[7];
  const float* cb  = (const float*)d_in[8];
  const float* afw = (const float*)d_in[9];
  const float* afb = (const float*)d_in[10];
  const float* cfw = (const float*)d_in[11];
  const float* cfb = (const float*)d_in[12];
  float* out = (float*)d_out;

  // ws layout: xb (13,107,200 B) | Y (144,000 B) | emb (48,000 B) | P (18,432,000 B)
  unsigned short* xb = (unsigned short*)d_ws;
  float* Y   = (float*)((char*)d_ws + 13107200);
  float* emb = Y + 6*NN*CO;
  float* P   = emb + 2*NN*CO;
  const size_t need_full = 13107200u + (size_t)(6*NN*CO + 2*NN*CO)*4 + (size_t)6*G_SPLIT*NN*CO*4;
  const int partial = (ws_size >= need_full) ? 1 : 0;

  hipMemsetAsync(Y, 0, 6*NN*CO*sizeof(float), stream);
  hipMemsetAsync(out, 0, 101*sizeof(float), stream);

  k_cvt<<<6400, 256, 0, stream>>>(x, xb);
  k_gemm<<<dim3(G_SPLIT,6), 256, 0, stream>>>(xb, aw, cw, partial ? P : Y, partial);
  if(partial){
    k_reduce<<<dim3((6*NN*CO+255)/256, 4), 256, 0, stream>>>(P, Y);
  }
  k_cheb<<<120, 128, 0, stream>>>(Y, ei, ab, cb, emb);
  k_fc<<<FCB+1, 256, 0, stream>>>(emb, afw, afb, cfw, cfb, s0, s1, s2, out);
}